// Round 6
// baseline (102.289 us; speedup 1.0000x reference)
//
#include <hip/hip_runtime.h>
#include <hip/hip_bf16.h>
#include <cstdint>

#define NV 64
#define NH 128
#define NB 16384
// ws layout: 130 c2-chunks (k=32 each; 128 for W2, 2 for W1^T) x 8 h-frags x 1 KB
#define FRAG_ELEMS (130 * 8 * 512)   // 532480 bf16 = 1064960 B

typedef __bf16 bf16x8_t __attribute__((ext_vector_type(8)));
typedef float f32x4_t __attribute__((ext_vector_type(4)));
typedef float f32x2_t __attribute__((ext_vector_type(2)));
typedef uint32_t u32x4_t __attribute__((ext_vector_type(4)));
typedef uint32_t u32x2_t __attribute__((ext_vector_type(2)));

__device__ __forceinline__ uint32_t bf16_rne(float f) {
  uint32_t u = __float_as_uint(f);
  return (u + 0x7fffu + ((u >> 16) & 1u)) >> 16;
}

// Pre-pass: emit bf16(0.5*W2) and bf16(W1^T) in MFMA-B-fragment-contiguous
// order. Fragment (c2, fh) is 1 KB: lane l bytes [l*16, l*16+16) hold
// B[n = fh*16 + (l&15)][k = c2*32 + (l>>4)*8 + t], t=0..7.
// W2 part: B[h][k] = 0.5*w2f[h*4096 + k] (k = i*64+j < 4096).
// W1 part (c2=128,129): B[h][j] = w1f[j*128 + h].
__global__ void cvt_kernel(const float* __restrict__ w1f,
                           const float* __restrict__ w2f,
                           uint16_t* __restrict__ frag) {
  int tg = blockIdx.x * 256 + threadIdx.x;
  if (tg < 128 * 512) {           // W2: thread = (h, k8); reads 32B contiguous
    int h = tg >> 9, k8 = tg & 511;
    const float* p = w2f + ((size_t)h << 12) + k8 * 8;
    float4 a = *(const float4*)p;
    float4 b = *(const float4*)(p + 4);
    uint4 o;
    o.x = (bf16_rne(0.5f * a.y) << 16) | bf16_rne(0.5f * a.x);
    o.y = (bf16_rne(0.5f * a.w) << 16) | bf16_rne(0.5f * a.z);
    o.z = (bf16_rne(0.5f * b.y) << 16) | bf16_rne(0.5f * b.x);
    o.w = (bf16_rne(0.5f * b.w) << 16) | bf16_rne(0.5f * b.z);
    int c2 = k8 >> 2, lhi = k8 & 3;
    int fh = h >> 4, l = lhi * 16 + (h & 15);
    *(uint4*)(frag + (((c2 * 8 + fh) * 64 + l) << 3)) = o;
  } else {                        // W1^T: thread = (h, j8)
    int t2 = tg - 128 * 512;      // [0, 1024)
    int h = t2 >> 3, j8 = t2 & 7;
    uint32_t v[8];
#pragma unroll
    for (int t = 0; t < 8; ++t)
      v[t] = bf16_rne(w1f[(j8 * 8 + t) * 128 + h]);
    int c2 = 128 + (j8 >> 2), lhi = j8 & 3;
    int fh = h >> 4, l = lhi * 16 + (h & 15);
    uint4 o;
    o.x = (v[1] << 16) | v[0];
    o.y = (v[3] << 16) | v[2];
    o.z = (v[5] << 16) | v[4];
    o.w = (v[7] << 16) | v[6];
    *(uint4*)(frag + (((c2 * 8 + fh) * 64 + l) << 3)) = o;
  }
}

// psi[m] = prod_h cos(bias[h] + sum_k G[m,k]*B[h,k]), K = 4160.
// k<4096: G = x_i*x_j (k=i*64+j), B = 0.5*W2[h,i,j]; k>=4096: G = x_j, B = W1T.
// B fragments load global->register (pre-swizzled ws layout): NO LDS and NO
// __syncthreads in the K-loop. Block = 4 waves; wave = 64m x 32h (4 im x 2 ih).
// s_i for the tail chunk comes from a sentinel 1.0 column in xtile.
__launch_bounds__(256, 2)
__global__ void rbm_kernel(const float* __restrict__ xg,
                           const float* __restrict__ biasg,
                           const __hip_bfloat16* __restrict__ frag,
                           float* __restrict__ outg) {
  __shared__ __align__(16) float xtile[64 * 68];  // stride 68; col 64 = 1.0
  __shared__ float part[4][64];

  const int tid  = threadIdx.x;
  const int hq   = tid >> 6;   // wave = h quarter (32 cols)
  const int lane = tid & 63;
  const int c15  = lane & 15;
  const int q    = lane >> 4;
  const int mblk = blockIdx.x * 64;

  // stage x tile (64 rows x 64 f32, stride 68)
  {
    int row = tid >> 2, seg = tid & 3;
    const float* p = xg + (size_t)(mblk + row) * NV + seg * 16;
    float4 v0 = *(const float4*)(p);
    float4 v1 = *(const float4*)(p + 4);
    float4 v2 = *(const float4*)(p + 8);
    float4 v3 = *(const float4*)(p + 12);
    float* d = &xtile[row * 68 + seg * 16];
    *(float4*)(d) = v0; *(float4*)(d + 4) = v1;
    *(float4*)(d + 8) = v2; *(float4*)(d + 12) = v3;
  }
  if (tid < 64) xtile[tid * 68 + 64] = 1.0f;  // s=1 sentinel for order-1 tail
  __syncthreads();

  // per-lane x (f32 pairs) from LDS: rows m = im*16+c15, cols jh*32+q*8+2t{,+1}
  f32x2_t xf[4][2][4];
  const float* xrow[4];
#pragma unroll
  for (int im = 0; im < 4; ++im) {
    xrow[im] = &xtile[(im * 16 + c15) * 68];
#pragma unroll
    for (int jh = 0; jh < 2; ++jh) {
      float4 a = *(const float4*)(xrow[im] + jh * 32 + q * 8);
      float4 b = *(const float4*)(xrow[im] + jh * 32 + q * 8 + 4);
      xf[im][jh][0] = f32x2_t{a.x, a.y};
      xf[im][jh][1] = f32x2_t{a.z, a.w};
      xf[im][jh][2] = f32x2_t{b.x, b.y};
      xf[im][jh][3] = f32x2_t{b.z, b.w};
    }
  }

  // B-fragment stream: wave hq reads frags (c2*8 + hq*2 + ih), lane offset l*8
  const __hip_bfloat16* pb = frag + (size_t)(hq * 2) * 512 + lane * 8;
  bf16x8_t bnxt[2][2];
#pragma unroll
  for (int jh = 0; jh < 2; ++jh)
#pragma unroll
    for (int ih = 0; ih < 2; ++ih)
      bnxt[jh][ih] = *(const bf16x8_t*)(pb + jh * 4096 + ih * 512);

  f32x4_t acc[4][2];
#pragma unroll
  for (int im = 0; im < 4; ++im)
#pragma unroll
    for (int ih = 0; ih < 2; ++ih)
      acc[im][ih] = (f32x4_t)0.0f;

  float scur[4];
#pragma unroll
  for (int im = 0; im < 4; ++im) scur[im] = xrow[im][0];

  for (int c = 0; c < 65; ++c) {
    bf16x8_t bc[2][2];
#pragma unroll
    for (int jh = 0; jh < 2; ++jh)
#pragma unroll
      for (int ih = 0; ih < 2; ++ih)
        bc[jh][ih] = bnxt[jh][ih];
    pb += 8192;  // next c (8 frags of 512 elems)
    if (c < 64) {
#pragma unroll
      for (int jh = 0; jh < 2; ++jh)
#pragma unroll
        for (int ih = 0; ih < 2; ++ih)
          bnxt[jh][ih] = *(const bf16x8_t*)(pb + jh * 4096 + ih * 512);
    }
    float s[4];
#pragma unroll
    for (int im = 0; im < 4; ++im) s[im] = scur[im];
    if (c < 64) {
#pragma unroll
      for (int im = 0; im < 4; ++im) scur[im] = xrow[im][c + 1];
    }
#pragma unroll
    for (int jh = 0; jh < 2; ++jh) {
      bf16x8_t afrag[4];
#pragma unroll
      for (int im = 0; im < 4; ++im) {
        const f32x2_t s2 = f32x2_t{s[im], s[im]};
        u32x4_t adv;
#pragma unroll
        for (int t = 0; t < 4; ++t) {
          f32x2_t pr = s2 * xf[im][jh][t];           // v_pk_mul_f32
          u32x2_t u = __builtin_bit_cast(u32x2_t, pr);
          adv[t] = __builtin_amdgcn_perm(u[1], u[0], 0x07060302);  // hi halves
        }
        afrag[im] = __builtin_bit_cast(bf16x8_t, adv);
      }
#pragma unroll
      for (int ih = 0; ih < 2; ++ih)
#pragma unroll
        for (int im = 0; im < 4; ++im)
          acc[im][ih] = __builtin_amdgcn_mfma_f32_16x16x32_bf16(
              afrag[im], bc[jh][ih], acc[im][ih], 0, 0, 0);
    }
  }

  // epilogue: a += bias; hw cos; product over h
  float bs[2];
#pragma unroll
  for (int ih = 0; ih < 2; ++ih)
    bs[ih] = biasg[hq * 32 + ih * 16 + c15];

  const float INV2PI = 0.15915494309189535f;
  float prod[4][4];
#pragma unroll
  for (int im = 0; im < 4; ++im)
#pragma unroll
    for (int r = 0; r < 4; ++r) {
      float c0 = __builtin_amdgcn_cosf((acc[im][0][r] + bs[0]) * INV2PI);
      float c1 = __builtin_amdgcn_cosf((acc[im][1][r] + bs[1]) * INV2PI);
      prod[im][r] = c0 * c1;
    }

  // product across the 16 h-columns held by lanes (width-16 butterfly)
#pragma unroll
  for (int ofs = 1; ofs < 16; ofs <<= 1)
#pragma unroll
    for (int im = 0; im < 4; ++im)
#pragma unroll
      for (int r = 0; r < 4; ++r)
        prod[im][r] *= __shfl_xor(prod[im][r], ofs, 16);

  if (c15 == 0) {
#pragma unroll
    for (int im = 0; im < 4; ++im)
#pragma unroll
      for (int r = 0; r < 4; ++r)
        part[hq][im * 16 + q * 4 + r] = prod[im][r];
  }
  __syncthreads();
  if (tid < 64) {
    float f = part[0][tid] * part[1][tid] * part[2][tid] * part[3][tid];
    outg[mblk + tid] = f;
  }
}

extern "C" void kernel_launch(void* const* d_in, const int* in_sizes, int n_in,
                              void* d_out, int out_size, void* d_ws, size_t ws_size,
                              hipStream_t stream) {
  const float* x   = (const float*)d_in[0];
  const float* w1f = (const float*)d_in[1];
  const float* w2f = (const float*)d_in[2];
  const float* hb  = (const float*)d_in[3];
  float* out = (float*)d_out;
  uint16_t* frag = (uint16_t*)d_ws;   // FRAG_ELEMS bf16
  (void)in_sizes; (void)n_in; (void)out_size; (void)ws_size;

  cvt_kernel<<<(128 * 512 + 1024) / 256, 256, 0, stream>>>(w1f, w2f, frag);
  rbm_kernel<<<NB / 64, 256, 0, stream>>>(
      x, hb, (const __hip_bfloat16*)frag, out);
}

// Round 7
// 85.983 us; speedup vs baseline: 1.1896x; 1.1896x over previous
//
#include <hip/hip_runtime.h>
#include <hip/hip_bf16.h>
#include <cstdint>

#define NV 64
#define NH 128
#define NB 16384
#define NCHUNK 37                 // 8 diag + 28 off-diag + 1 order-1, 64 k each
#define FRAG_ELEMS (NCHUNK * 8192)  // 303104 bf16 = 592 KB in d_ws

typedef __bf16 bf16x8_t __attribute__((ext_vector_type(8)));
typedef float f32x4_t __attribute__((ext_vector_type(4)));
typedef float f32x2_t __attribute__((ext_vector_type(2)));
typedef uint32_t u32x4_t __attribute__((ext_vector_type(4)));
typedef uint32_t u32x2_t __attribute__((ext_vector_type(2)));

__device__ __forceinline__ uint32_t bf16_rne(float f) {
  uint32_t u = __float_as_uint(f);
  return (u + 0x7fffu + ((u >> 16) & 1u)) >> 16;
}

// Pre-pass: build B' in MFMA-B-fragment order, symmetrized group-triangle:
//  chunk c<8 (diag, I=J=c):    B'[h, slot(a,b)] = 0.5*W2[h, I8+a, I8+b]
//  chunk 8..35 (off, I<J):     B'[h, slot(a,b)] = 0.5*(W2[h,i,j]+W2[h,j,i])
//  chunk 36 (order-1):         B'[h, slot=j]    = W1[j, h]
// Fragment (c2 = c*2+jh, fh): lane l holds B'[h = fh*16+(l&15)]
//   [k = slot = jh*32 + (l>>4)*8 + t], elem offset ((c2*8+fh)*512 + l*8 + t).
__global__ void cvt_kernel(const float* __restrict__ w1f,
                           const float* __restrict__ w2f,
                           uint16_t* __restrict__ frag) {
  int tg = blockIdx.x * 256 + threadIdx.x;   // < 74*8*64 = 37888
  int l = tg & 63, fh = (tg >> 6) & 7, c2 = tg >> 9;
  int chunk = c2 >> 1, jh = c2 & 1;
  int h = fh * 16 + (l & 15);
  int kb = jh * 32 + (l >> 4) * 8;
  uint32_t o16[8];
#pragma unroll
  for (int t = 0; t < 8; ++t) {
    int slot = kb + t;
    float v;
    if (chunk < 8) {
      int i = chunk * 8 + (slot >> 3), j = chunk * 8 + (slot & 7);
      v = 0.5f * w2f[h * 4096 + i * 64 + j];
    } else if (chunk < 36) {
      int o = chunk - 8, I = 0;
      while (o >= 7 - I) { o -= 7 - I; ++I; }
      int J = I + 1 + o;
      int i = I * 8 + (slot >> 3), j = J * 8 + (slot & 7);
      v = 0.5f * (w2f[h * 4096 + i * 64 + j] + w2f[h * 4096 + j * 64 + i]);
    } else {
      v = w1f[slot * 128 + h];
    }
    o16[t] = bf16_rne(v);
  }
  uint4 o;
  o.x = (o16[1] << 16) | o16[0];
  o.y = (o16[3] << 16) | o16[2];
  o.z = (o16[5] << 16) | o16[4];
  o.w = (o16[7] << 16) | o16[6];
  *(uint4*)(frag + ((size_t)(c2 * 8 + fh) << 9) + l * 8) = o;
}

// psi[m] = prod_h cos(bias[h] + sum_k A[m,k] B'[h,k]), K = 37*64.
// Main chunks: A[m, slot(a,b)] = x[m, I8+a] * x[m, J8+b]; s = x[I8+a] from LDS
// (a = jh*4+q static per jh), xB = group-J row registers. Tail: A = x_j.
// 8 waves = 2 m-halves x 4 h-quarters; grid 256 -> 2 waves/SIMD; K-loop fully
// unrolled, zero barriers, depth-1 register prefetch of B-frags (L1 dedups the
// m-half wave pair's identical B reads).
__launch_bounds__(512, 2)
__global__ void rbm_kernel(const float* __restrict__ xg,
                           const float* __restrict__ biasg,
                           const __hip_bfloat16* __restrict__ frag,
                           float* __restrict__ outg) {
  __shared__ __align__(16) float xtile[64 * 76];  // cols 64..71 = 1.0 sentinel
  __shared__ float part[4][64];

  const int tid  = threadIdx.x;
  const int wv   = tid >> 6;
  const int wm   = wv & 1;     // m half (32 rows)
  const int hq   = wv >> 1;    // h quarter (32 cols)
  const int lane = tid & 63;
  const int c15  = lane & 15;
  const int q    = lane >> 4;
  const int mblk = blockIdx.x * 64;

  // chunk -> (I, J) tables (compile-time folded under full unroll)
  constexpr int CI[36] = {0,1,2,3,4,5,6,7, 0,0,0,0,0,0,0, 1,1,1,1,1,1,
                          2,2,2,2,2, 3,3,3,3, 4,4,4, 5,5, 6};
  constexpr int CJ[36] = {0,1,2,3,4,5,6,7, 1,2,3,4,5,6,7, 2,3,4,5,6,7,
                          3,4,5,6,7, 4,5,6,7, 5,6,7, 6,7, 7};

  // stage x tile (64 rows x 64 f32, stride 76) + sentinel cols
  {
    int row = tid >> 3, grp = tid & 7;
    const float* p = xg + (size_t)(mblk + row) * NV + grp * 8;
    float4 a = *(const float4*)(p);
    float4 b = *(const float4*)(p + 4);
    *(float4*)(&xtile[row * 76 + grp * 8]) = a;
    *(float4*)(&xtile[row * 76 + grp * 8 + 4]) = b;
    xtile[row * 76 + 64 + grp] = 1.0f;
  }
  __syncthreads();

  // per-lane full x rows (f32 pairs) for the two m-rows this lane owns
  const float* sx[2];
  f32x2_t xb[2][32];   // xb[im][g*4+tt] = {x[g*8+2tt], x[g*8+2tt+1]}
#pragma unroll
  for (int im = 0; im < 2; ++im) {
    sx[im] = &xtile[(wm * 32 + im * 16 + c15) * 76];
#pragma unroll
    for (int g = 0; g < 8; ++g) {
      float4 a = *(const float4*)(sx[im] + g * 8);
      float4 b = *(const float4*)(sx[im] + g * 8 + 4);
      xb[im][g * 4 + 0] = f32x2_t{a.x, a.y};
      xb[im][g * 4 + 1] = f32x2_t{a.z, a.w};
      xb[im][g * 4 + 2] = f32x2_t{b.x, b.y};
      xb[im][g * 4 + 3] = f32x2_t{b.z, b.w};
    }
  }

  // B-fragment base: wave hq, frag (c*2+jh, hq*2+ih), lane offset l*8
  const __hip_bfloat16* pw = frag + (size_t)hq * 1024 + lane * 8;

  f32x4_t acc[2][2];
#pragma unroll
  for (int im = 0; im < 2; ++im)
#pragma unroll
    for (int ih = 0; ih < 2; ++ih)
      acc[im][ih] = (f32x4_t)0.0f;

  bf16x8_t bn[2][2];
#pragma unroll
  for (int jh = 0; jh < 2; ++jh)
#pragma unroll
    for (int ih = 0; ih < 2; ++ih)
      bn[jh][ih] = *(const bf16x8_t*)(pw + jh * 4096 + ih * 512);

#pragma unroll
  for (int c = 0; c < 36; ++c) {
    bf16x8_t bc[2][2];
#pragma unroll
    for (int jh = 0; jh < 2; ++jh)
#pragma unroll
      for (int ih = 0; ih < 2; ++ih)
        bc[jh][ih] = bn[jh][ih];
    {  // prefetch chunk c+1
      const __hip_bfloat16* pn = pw + (size_t)(c + 1) * 8192;
#pragma unroll
      for (int jh = 0; jh < 2; ++jh)
#pragma unroll
        for (int ih = 0; ih < 2; ++ih)
          bn[jh][ih] = *(const bf16x8_t*)(pn + jh * 4096 + ih * 512);
    }
    const int I = CI[c], J = CJ[c];
#pragma unroll
    for (int jh = 0; jh < 2; ++jh) {
      bf16x8_t afrag[2];
#pragma unroll
      for (int im = 0; im < 2; ++im) {
        float s = sx[im][I * 8 + jh * 4 + q];   // LDS b32, 2-way max
        const f32x2_t s2 = f32x2_t{s, s};
        u32x4_t adv;
#pragma unroll
        for (int tt = 0; tt < 4; ++tt) {
          f32x2_t pr = s2 * xb[im][J * 4 + tt];          // v_pk_mul_f32
          u32x2_t u = __builtin_bit_cast(u32x2_t, pr);
          adv[tt] = __builtin_amdgcn_perm(u[1], u[0], 0x07060302);
        }
        afrag[im] = __builtin_bit_cast(bf16x8_t, adv);
      }
#pragma unroll
      for (int ih = 0; ih < 2; ++ih)
#pragma unroll
        for (int im = 0; im < 2; ++im)
          acc[im][ih] = __builtin_amdgcn_mfma_f32_16x16x32_bf16(
              afrag[im], bc[jh][ih], acc[im][ih], 0, 0, 0);
    }
  }

  // order-1 tail (chunk 36, bn holds its frags): A = x_j straight from LDS
#pragma unroll
  for (int jh = 0; jh < 2; ++jh) {
    bf16x8_t afrag[2];
#pragma unroll
    for (int im = 0; im < 2; ++im) {
      float4 a = *(const float4*)(sx[im] + jh * 32 + q * 8);
      float4 b = *(const float4*)(sx[im] + jh * 32 + q * 8 + 4);
      const float pr[4][2] = {{a.x, a.y}, {a.z, a.w}, {b.x, b.y}, {b.z, b.w}};
      u32x4_t adv;
#pragma unroll
      for (int tt = 0; tt < 4; ++tt)
        adv[tt] = __builtin_amdgcn_perm(__float_as_uint(pr[tt][1]),
                                        __float_as_uint(pr[tt][0]), 0x07060302);
      afrag[im] = __builtin_bit_cast(bf16x8_t, adv);
    }
#pragma unroll
    for (int ih = 0; ih < 2; ++ih)
#pragma unroll
      for (int im = 0; im < 2; ++im)
        acc[im][ih] = __builtin_amdgcn_mfma_f32_16x16x32_bf16(
            afrag[im], bn[jh][ih], acc[im][ih], 0, 0, 0);
  }

  // epilogue: a += bias; hw cos (input in revolutions); product over h
  float bs[2];
#pragma unroll
  for (int ih = 0; ih < 2; ++ih)
    bs[ih] = biasg[hq * 32 + ih * 16 + c15];

  const float INV2PI = 0.15915494309189535f;
  float prod[2][4];
#pragma unroll
  for (int im = 0; im < 2; ++im)
#pragma unroll
    for (int r = 0; r < 4; ++r) {
      float c0 = __builtin_amdgcn_cosf((acc[im][0][r] + bs[0]) * INV2PI);
      float c1 = __builtin_amdgcn_cosf((acc[im][1][r] + bs[1]) * INV2PI);
      prod[im][r] = c0 * c1;
    }

  // product across the 16 h-columns held by lanes (width-16 butterfly)
#pragma unroll
  for (int ofs = 1; ofs < 16; ofs <<= 1)
#pragma unroll
    for (int im = 0; im < 2; ++im)
#pragma unroll
      for (int r = 0; r < 4; ++r)
        prod[im][r] *= __shfl_xor(prod[im][r], ofs, 16);

  if (c15 == 0) {
#pragma unroll
    for (int im = 0; im < 2; ++im)
#pragma unroll
      for (int r = 0; r < 4; ++r)
        part[hq][wm * 32 + im * 16 + q * 4 + r] = prod[im][r];
  }
  __syncthreads();
  if (tid < 64) {
    float f = part[0][tid] * part[1][tid] * part[2][tid] * part[3][tid];
    outg[mblk + tid] = f;
  }
}

extern "C" void kernel_launch(void* const* d_in, const int* in_sizes, int n_in,
                              void* d_out, int out_size, void* d_ws, size_t ws_size,
                              hipStream_t stream) {
  const float* x   = (const float*)d_in[0];
  const float* w1f = (const float*)d_in[1];
  const float* w2f = (const float*)d_in[2];
  const float* hb  = (const float*)d_in[3];
  float* out = (float*)d_out;
  uint16_t* frag = (uint16_t*)d_ws;   // FRAG_ELEMS bf16 (592 KB)
  (void)in_sizes; (void)n_in; (void)out_size; (void)ws_size;

  cvt_kernel<<<148, 256, 0, stream>>>(w1f, w2f, frag);
  rbm_kernel<<<NB / 64, 512, 0, stream>>>(
      x, hb, (const __hip_bfloat16*)frag, out);
}